// Round 2
// baseline (73.030 us; speedup 1.0000x reference)
//
#include <hip/hip_runtime.h>
#include <hip/hip_bf16.h>

typedef __bf16 bf16x8 __attribute__((ext_vector_type(8)));
typedef float f32x4 __attribute__((ext_vector_type(4)));

#define G 8
#define B 32
#define D 32
#define O 32
#define K 4096   // N*T
#define T 64
#define KSPLIT 8
#define KCHUNK (K / KSPLIT)  // 512

// ws layout: [0, 8MB): XMT bf16 [O][B][K]; then S f32 [KSPLIT][G][O][D][B] (8 MB)
#define XMT_ELEMS (O * B * K)              // 4,194,304 bf16 = 8 MB
#define S_ELEMS   (KSPLIT * G * O * D * B) // 2,097,152 f32  = 8 MB

// XMT[o][b][k] = x[b][k] * mask[o][k%64], as bf16. k = n*64+t, x flat idx = b*K+k.
__global__ __launch_bounds__(256) void prep_xmt(const float* __restrict__ x,
                                                const float* __restrict__ mask,
                                                __bf16* __restrict__ xmt) {
    int tid = blockIdx.x * 256 + threadIdx.x;   // 524288 threads, 8 elems each
    int o = tid >> 14;
    int b = (tid >> 9) & 31;
    int k = (tid & 511) << 3;
    int t = k & 63;
    const float4 x0 = *(const float4*)(x + b * K + k);
    const float4 x1 = *(const float4*)(x + b * K + k + 4);
    const float4 m0 = *(const float4*)(mask + o * T + t);
    const float4 m1 = *(const float4*)(mask + o * T + t + 4);
    bf16x8 r;
    r[0] = (__bf16)(x0.x * m0.x); r[1] = (__bf16)(x0.y * m0.y);
    r[2] = (__bf16)(x0.z * m0.z); r[3] = (__bf16)(x0.w * m0.w);
    r[4] = (__bf16)(x1.x * m1.x); r[5] = (__bf16)(x1.y * m1.y);
    r[6] = (__bf16)(x1.z * m1.z); r[7] = (__bf16)(x1.w * m1.w);
    *(bf16x8*)(xmt + (size_t)(o * B + b) * K + k) = r;
}

// S[ks][g][o][d][b] = sum over k in ks-chunk of W[g][d][o][k] * XMT[o][b][k]
// Block = (o, g, ks), 128 threads = 2 waves; wave w covers d in [16w, 16w+16).
__global__ __launch_bounds__(128) void gemm_main(const float* __restrict__ W,
                                                 const __bf16* __restrict__ xmt,
                                                 float* __restrict__ S) {
    const int o = blockIdx.x, g = blockIdx.y, ks = blockIdx.z;
    const int wave = threadIdx.x >> 6;
    const int lane = threadIdx.x & 63;
    const int dbase = wave * 16;
    const int d = dbase + (lane & 15);
    const int klane = (lane >> 4) * 8;

    const float*  wrow = W + (size_t)((g * D + d) * O + o) * K + ks * KCHUNK + klane;
    const __bf16* xr0  = xmt + (size_t)(o * B + (lane & 15)) * K + ks * KCHUNK + klane;
    const __bf16* xr1  = xr0 + (size_t)16 * K;

    f32x4 acc0 = {0.f, 0.f, 0.f, 0.f};
    f32x4 acc1 = {0.f, 0.f, 0.f, 0.f};

    #pragma unroll 8
    for (int s = 0; s < KCHUNK / 32; ++s) {
        // W is a read-once 128MB stream: nontemporal, keep XMT/S in L2.
        const f32x4 wa = __builtin_nontemporal_load((const f32x4*)(wrow + s * 32));
        const f32x4 wb = __builtin_nontemporal_load((const f32x4*)(wrow + s * 32 + 4));
        bf16x8 af;
        af[0] = (__bf16)wa[0]; af[1] = (__bf16)wa[1];
        af[2] = (__bf16)wa[2]; af[3] = (__bf16)wa[3];
        af[4] = (__bf16)wb[0]; af[5] = (__bf16)wb[1];
        af[6] = (__bf16)wb[2]; af[7] = (__bf16)wb[3];
        const bf16x8 bf0 = *(const bf16x8*)(xr0 + s * 32);
        const bf16x8 bf1 = *(const bf16x8*)(xr1 + s * 32);
        acc0 = __builtin_amdgcn_mfma_f32_16x16x32_bf16(af, bf0, acc0, 0, 0, 0);
        acc1 = __builtin_amdgcn_mfma_f32_16x16x32_bf16(af, bf1, acc1, 0, 0, 0);
    }

    // C/D layout (m89-verified): lane holds D[row=(lane>>4)*4+r][col=lane&15]
    float* Sp = S + (size_t)(((ks * G + g) * O + o) * D + dbase) * B;
    const int r0 = (lane >> 4) * 4, c = lane & 15;
    #pragma unroll
    for (int r = 0; r < 4; ++r) {
        Sp[(r0 + r) * B + c]      = acc0[r];
        Sp[(r0 + r) * B + 16 + c] = acc1[r];
    }
}

// out[b][d][o] = bias[d][o] + sum_g y[b][g] * sum_ks S[ks][g][o][d][b]
__global__ __launch_bounds__(256) void reduce_out(const float* __restrict__ S,
                                                  const float* __restrict__ y,
                                                  const float* __restrict__ bias,
                                                  float* __restrict__ out) {
    int tid = blockIdx.x * 256 + threadIdx.x;   // 32768 = B*D*O
    int o = tid & 31, d = (tid >> 5) & 31, b = tid >> 10;
    float acc = bias[d * O + o];
    #pragma unroll
    for (int g = 0; g < G; ++g) {
        float s = 0.f;
        #pragma unroll
        for (int ks = 0; ks < KSPLIT; ++ks)
            s += S[(size_t)(((ks * G + g) * O + o) * D + d) * B + b];
        acc += y[b * G + g] * s;
    }
    out[tid] = acc;
}

extern "C" void kernel_launch(void* const* d_in, const int* in_sizes, int n_in,
                              void* d_out, int out_size, void* d_ws, size_t ws_size,
                              hipStream_t stream) {
    const float* x    = (const float*)d_in[0];
    const float* y    = (const float*)d_in[1];
    const float* w    = (const float*)d_in[2];
    const float* bias = (const float*)d_in[3];
    const float* mask = (const float*)d_in[4];
    float* out = (float*)d_out;

    __bf16* xmt = (__bf16*)d_ws;
    float*  S   = (float*)((char*)d_ws + (size_t)XMT_ELEMS * sizeof(__bf16));

    prep_xmt<<<2048, 256, 0, stream>>>(x, mask, xmt);
    gemm_main<<<dim3(O, G, KSPLIT), 128, 0, stream>>>(w, xmt, S);
    reduce_out<<<128, 256, 0, stream>>>(S, y, bias, out);
}

// Round 3
// 54.871 us; speedup vs baseline: 1.3309x; 1.3309x over previous
//
#include <hip/hip_runtime.h>
#include <hip/hip_bf16.h>

typedef __bf16 bf16x8 __attribute__((ext_vector_type(8)));
typedef float f32x4 __attribute__((ext_vector_type(4)));

#define G 8
#define B 32
#define D 32
#define O 32
#define K 4096   // N*T
#define T 64
#define KSPLIT 8
#define KCHUNK (K / KSPLIT)  // 512
#define NKT (K / 32)         // 128 k-tiles of 32

// ws layout: [0, 8MB): XMT bf16 [O][NKT][B][32]; then S f32 [KSPLIT][G][O][D][B] (8 MB)
#define XMT_ELEMS (O * B * K)              // 4,194,304 bf16 = 8 MB
#define S_ELEMS   (KSPLIT * G * O * D * B) // 2,097,152 f32  = 8 MB

// XMT[o][kt][b][k5] = x[b][kt*32+k5] * mask[o][(kt*32+k5)%64], as bf16.
// This is exactly the MFMA B-fragment order: a wave's fragment load for
// (o, kt) is one contiguous 1KB transaction.
__global__ __launch_bounds__(256) void prep_xmt(const float* __restrict__ x,
                                                const float* __restrict__ mask,
                                                __bf16* __restrict__ xmt) {
    int tid = blockIdx.x * 256 + threadIdx.x;   // 524288 threads, 8 elems each
    int o  = tid >> 14;
    int kt = (tid >> 7) & 127;
    int b  = (tid >> 2) & 31;
    int c  = tid & 3;
    int k  = kt * 32 + c * 8;
    int t  = k & 63;
    const float4 x0 = *(const float4*)(x + b * K + k);
    const float4 x1 = *(const float4*)(x + b * K + k + 4);
    const float4 m0 = *(const float4*)(mask + o * T + t);
    const float4 m1 = *(const float4*)(mask + o * T + t + 4);
    bf16x8 r;
    r[0] = (__bf16)(x0.x * m0.x); r[1] = (__bf16)(x0.y * m0.y);
    r[2] = (__bf16)(x0.z * m0.z); r[3] = (__bf16)(x0.w * m0.w);
    r[4] = (__bf16)(x1.x * m1.x); r[5] = (__bf16)(x1.y * m1.y);
    r[6] = (__bf16)(x1.z * m1.z); r[7] = (__bf16)(x1.w * m1.w);
    // flat elem index == tid*8 by construction: fully coalesced store
    *(bf16x8*)(xmt + (size_t)tid * 8) = r;
}

// S[ks][g][o][d][b] = sum over k in ks-chunk of W[g][d][o][k] * XMT(o,b,k)
// Block = (o, g, ks), 128 threads = 2 waves; wave w covers d in [16w, 16w+16).
__global__ __launch_bounds__(128) void gemm_main(const float* __restrict__ W,
                                                 const __bf16* __restrict__ xmt,
                                                 float* __restrict__ S) {
    const int o = blockIdx.x, g = blockIdx.y, ks = blockIdx.z;
    const int wave = threadIdx.x >> 6;
    const int lane = threadIdx.x & 63;
    const int dbase = wave * 16;
    const int d = dbase + (lane & 15);
    const int klane = (lane >> 4) * 8;

    const float* wrow = W + (size_t)((g * D + d) * O + o) * K + ks * KCHUNK + klane;
    // XMT tile base for (o, kt = ks*KCHUNK/32): [o][kt][b][32]
    const __bf16* xt = xmt + ((size_t)(o * NKT + ks * (KCHUNK / 32)) * B) * 32
                           + (lane & 15) * 32 + klane;

    f32x4 acc0 = {0.f, 0.f, 0.f, 0.f};
    f32x4 acc1 = {0.f, 0.f, 0.f, 0.f};

    #pragma unroll 4
    for (int s = 0; s < KCHUNK / 32; ++s) {
        const f32x4 wa = *(const f32x4*)(wrow + s * 32);
        const f32x4 wb = *(const f32x4*)(wrow + s * 32 + 4);
        bf16x8 af;
        af[0] = (__bf16)wa[0]; af[1] = (__bf16)wa[1];
        af[2] = (__bf16)wa[2]; af[3] = (__bf16)wa[3];
        af[4] = (__bf16)wb[0]; af[5] = (__bf16)wb[1];
        af[6] = (__bf16)wb[2]; af[7] = (__bf16)wb[3];
        const bf16x8 bf0 = *(const bf16x8*)(xt + (size_t)s * 1024);        // b 0..15
        const bf16x8 bf1 = *(const bf16x8*)(xt + (size_t)s * 1024 + 512);  // b 16..31
        acc0 = __builtin_amdgcn_mfma_f32_16x16x32_bf16(af, bf0, acc0, 0, 0, 0);
        acc1 = __builtin_amdgcn_mfma_f32_16x16x32_bf16(af, bf1, acc1, 0, 0, 0);
    }

    // C/D layout (m89-verified): lane holds D[row=(lane>>4)*4+r][col=lane&15]
    float* Sp = S + (size_t)(((ks * G + g) * O + o) * D + dbase) * B;
    const int r0 = (lane >> 4) * 4, c = lane & 15;
    #pragma unroll
    for (int r = 0; r < 4; ++r) {
        Sp[(r0 + r) * B + c]      = acc0[r];
        Sp[(r0 + r) * B + 16 + c] = acc1[r];
    }
}

// out[b][d][o] = bias[d][o] + sum_g y[b][g] * sum_ks S[ks][g][o][d][b]
__global__ __launch_bounds__(256) void reduce_out(const float* __restrict__ S,
                                                  const float* __restrict__ y,
                                                  const float* __restrict__ bias,
                                                  float* __restrict__ out) {
    int tid = blockIdx.x * 256 + threadIdx.x;   // 32768 = B*D*O
    int o = tid & 31, d = (tid >> 5) & 31, b = tid >> 10;
    float acc = bias[d * O + o];
    #pragma unroll
    for (int g = 0; g < G; ++g) {
        float s = 0.f;
        #pragma unroll
        for (int ks = 0; ks < KSPLIT; ++ks)
            s += S[(size_t)(((ks * G + g) * O + o) * D + d) * B + b];
        acc += y[b * G + g] * s;
    }
    out[tid] = acc;
}

extern "C" void kernel_launch(void* const* d_in, const int* in_sizes, int n_in,
                              void* d_out, int out_size, void* d_ws, size_t ws_size,
                              hipStream_t stream) {
    const float* x    = (const float*)d_in[0];
    const float* y    = (const float*)d_in[1];
    const float* w    = (const float*)d_in[2];
    const float* bias = (const float*)d_in[3];
    const float* mask = (const float*)d_in[4];
    float* out = (float*)d_out;

    __bf16* xmt = (__bf16*)d_ws;
    float*  S   = (float*)((char*)d_ws + (size_t)XMT_ELEMS * sizeof(__bf16));

    prep_xmt<<<2048, 256, 0, stream>>>(x, mask, xmt);
    gemm_main<<<dim3(O, G, KSPLIT), 128, 0, stream>>>(w, xmt, S);
    reduce_out<<<128, 256, 0, stream>>>(S, y, bias, out);
}

// Round 4
// 36.719 us; speedup vs baseline: 1.9889x; 1.4943x over previous
//
#include <hip/hip_runtime.h>
#include <hip/hip_bf16.h>

typedef __bf16 bf16x8 __attribute__((ext_vector_type(8)));
typedef float f32x4 __attribute__((ext_vector_type(4)));

#define G 8
#define B 32
#define D 32
#define O 32
#define K 4096   // N*T
#define T 64
#define KSPLIT 2
#define KCHUNK (K / KSPLIT)   // 2048 floats per row per block
#define BK 256                // floats staged per row per outer step (1KB)
#define NSTEP (KCHUNK / BK)   // 8
#define NKT (K / 32)          // 128 k-tiles of 32

// ws: [0,8MB) XMT bf16 [O][NKT][B][32]; then S f32 [KSPLIT][G][O][D][B] (2MB)
#define XMT_ELEMS (O * B * K)
#define S_ELEMS   (KSPLIT * G * O * D * B)

// XMT[o][kt][b][k5] = x[b][kt*32+k5] * mask[o][(kt*32+k5)%64]  (MFMA B-frag order)
__global__ __launch_bounds__(256) void prep_xmt(const float* __restrict__ x,
                                                const float* __restrict__ mask,
                                                __bf16* __restrict__ xmt) {
    int tid = blockIdx.x * 256 + threadIdx.x;   // 524288 threads, 8 elems each
    int o  = tid >> 14;
    int kt = (tid >> 7) & 127;
    int b  = (tid >> 2) & 31;
    int c  = tid & 3;
    int k  = kt * 32 + c * 8;
    int t  = k & 63;
    const float4 x0 = *(const float4*)(x + b * K + k);
    const float4 x1 = *(const float4*)(x + b * K + k + 4);
    const float4 m0 = *(const float4*)(mask + o * T + t);
    const float4 m1 = *(const float4*)(mask + o * T + t + 4);
    bf16x8 r;
    r[0] = (__bf16)(x0.x * m0.x); r[1] = (__bf16)(x0.y * m0.y);
    r[2] = (__bf16)(x0.z * m0.z); r[3] = (__bf16)(x0.w * m0.w);
    r[4] = (__bf16)(x1.x * m1.x); r[5] = (__bf16)(x1.y * m1.y);
    r[6] = (__bf16)(x1.z * m1.z); r[7] = (__bf16)(x1.w * m1.w);
    *(bf16x8*)(xmt + (size_t)tid * 8) = r;
}

// Block (o,g,ks): all 32 d x 32 b for one (g,o), K-half ks.
// 4 waves: wave w -> (bh = w&1, dh = w>>1) 16x16 output quadrant.
// W staged via global_load_lds (1KB contiguous per instr per d-row),
// XOR chunk-swizzle (row&7)<<4 applied to source AND lds-read addresses.
__global__ __launch_bounds__(256) void gemm_main(const float* __restrict__ W,
                                                 const __bf16* __restrict__ xmt,
                                                 float* __restrict__ S) {
    __shared__ float ldsW[2][32 * BK];   // 2 x 32 KB
    const int o  = blockIdx.x, g = blockIdx.y, ks = blockIdx.z;
    const int wid  = threadIdx.x >> 6;
    const int lane = threadIdx.x & 63;
    const int bh = wid & 1, dh = wid >> 1;
    const int l15 = lane & 15, g16 = lane >> 4;

    // A-fragment read: row r, chunk c0 = s*8 + g16*2 (swizzled)
    const int r = dh * 16 + l15;
    const int lds_ro = r * 1024 + ((g16 * 32) ^ ((r & 7) * 16));  // byte offset

    // XMT per-lane base: (o, kt0 = ks*64), b = bh*16+l15, k-sub g16*8
    const __bf16* xb = xmt + ((size_t)o * 128 + ks * 64) * 1024
                           + (bh * 16 + l15) * 32 + g16 * 8;

    // staging: wave stages rows d = 8*wid .. 8*wid+7; lane source chunk XOR (d&7)
    const size_t wrow0 = ((size_t)(g * D + 8 * wid) * O + o) * K + (size_t)ks * KCHUNK;

    f32x4 acc = {0.f, 0.f, 0.f, 0.f};

#define STAGE(buf, step)                                                          \
    {                                                                             \
        _Pragma("unroll")                                                         \
        for (int i = 0; i < 8; ++i) {                                             \
            const int d = 8 * wid + i;                                            \
            const char* src = (const char*)(W + wrow0 + (size_t)i * (O * K)       \
                                            + (size_t)(step) * BK)                \
                              + ((lane * 16) ^ ((d & 7) * 16));                   \
            __builtin_amdgcn_global_load_lds(                                     \
                (const __attribute__((address_space(1))) void*)src,               \
                (__attribute__((address_space(3))) void*)((char*)&ldsW[buf][0]    \
                                                          + d * 1024),            \
                16, 0, 0);                                                        \
        }                                                                         \
    }

    STAGE(0, 0);
    __syncthreads();

    int cur = 0;
    for (int step = 0; step < NSTEP; ++step) {
        if (step + 1 < NSTEP) STAGE(cur ^ 1, step + 1);

        const char* lb = (const char*)&ldsW[cur][0];
        const __bf16* xs = xb + (size_t)(step * 8) * 1024;
        #pragma unroll
        for (int s = 0; s < 8; ++s) {
            const int a0 = lds_ro + s * 128;
            const f32x4 alo = *(const f32x4*)(lb + a0);
            const f32x4 ahi = *(const f32x4*)(lb + (a0 ^ 16));
            bf16x8 af;
            af[0] = (__bf16)alo[0]; af[1] = (__bf16)alo[1];
            af[2] = (__bf16)alo[2]; af[3] = (__bf16)alo[3];
            af[4] = (__bf16)ahi[0]; af[5] = (__bf16)ahi[1];
            af[6] = (__bf16)ahi[2]; af[7] = (__bf16)ahi[3];
            const bf16x8 bfr = *(const bf16x8*)(xs + (size_t)s * 1024);
            acc = __builtin_amdgcn_mfma_f32_16x16x32_bf16(af, bfr, acc, 0, 0, 0);
        }
        __syncthreads();
        cur ^= 1;
    }
#undef STAGE

    // C/D: lane holds D[row=g16*4+i][col=l15] of its 16x16 quadrant
    float* Sp = S + (((size_t)(ks * G + g) * O + o) * D + dh * 16) * B + bh * 16;
    #pragma unroll
    for (int i = 0; i < 4; ++i)
        Sp[(g16 * 4 + i) * B + l15] = acc[i];
}

// out[b][d][o] = bias[d][o] + sum_g y[b][g] * sum_ks S[ks][g][o][d][b]
// Thread tid = (o,d,b) S-order: S reads fully coalesced; out writes scattered (tiny).
__global__ __launch_bounds__(256) void reduce_out(const float* __restrict__ S,
                                                  const float* __restrict__ y,
                                                  const float* __restrict__ bias,
                                                  float* __restrict__ out) {
    int tid = blockIdx.x * 256 + threadIdx.x;   // 32768 = O*D*B
    int o = tid >> 10, d = (tid >> 5) & 31, b = tid & 31;
    float acc = bias[d * O + o];
    #pragma unroll
    for (int g = 0; g < G; ++g) {
        float s = S[(size_t)g * (O * D * B) + tid]
                + S[(size_t)(G + g) * (O * D * B) + tid];
        acc += y[b * G + g] * s;
    }
    out[b * (D * O) + d * O + o] = acc;
}

extern "C" void kernel_launch(void* const* d_in, const int* in_sizes, int n_in,
                              void* d_out, int out_size, void* d_ws, size_t ws_size,
                              hipStream_t stream) {
    const float* x    = (const float*)d_in[0];
    const float* y    = (const float*)d_in[1];
    const float* w    = (const float*)d_in[2];
    const float* bias = (const float*)d_in[3];
    const float* mask = (const float*)d_in[4];
    float* out = (float*)d_out;

    __bf16* xmt = (__bf16*)d_ws;
    float*  S   = (float*)((char*)d_ws + (size_t)XMT_ELEMS * sizeof(__bf16));

    prep_xmt<<<2048, 256, 0, stream>>>(x, mask, xmt);
    gemm_main<<<dim3(O, G, KSPLIT), 256, 0, stream>>>(w, xmt, S);
    reduce_out<<<128, 256, 0, stream>>>(S, y, bias, out);
}

// Round 5
// 36.543 us; speedup vs baseline: 1.9984x; 1.0048x over previous
//
#include <hip/hip_runtime.h>
#include <hip/hip_bf16.h>

typedef __bf16 bf16x8 __attribute__((ext_vector_type(8)));
typedef float f32x4 __attribute__((ext_vector_type(4)));

#define G 8
#define B 32
#define D 32
#define O 32
#define K 4096   // N*T
#define T 64
#define KSPLIT 2
#define KCHUNK (K / KSPLIT)   // 2048 floats per row per block
#define BK 256                // floats staged per row per step (1KB)
#define NSTEP (KCHUNK / BK)   // 8

// ws: [0, 256KB) XB bf16 [K/32][B][32]; then S f32 [KSPLIT][G][D][O][B] (2MB)
#define XB_ELEMS (B * K)                   // 131072 bf16 = 256 KB
#define S_ELEMS  (KSPLIT * G * D * O * B)  // 524288 f32  = 2 MB

// XB[kt][b][k5] = bf16(x[b][kt*32+k5])  -- MFMA B-fragment order, no mask.
__global__ __launch_bounds__(256) void prep_xb(const float* __restrict__ x,
                                               __bf16* __restrict__ xb) {
    int tid = blockIdx.x * 256 + threadIdx.x;   // 16384 threads, 8 elems each
    int kt = tid >> 7;
    int b  = (tid >> 2) & 31;
    int c  = tid & 3;
    int k  = kt * 32 + c * 8;
    const float4 x0 = *(const float4*)(x + b * K + k);
    const float4 x1 = *(const float4*)(x + b * K + k + 4);
    bf16x8 r;
    r[0] = (__bf16)x0.x; r[1] = (__bf16)x0.y; r[2] = (__bf16)x0.z; r[3] = (__bf16)x0.w;
    r[4] = (__bf16)x1.x; r[5] = (__bf16)x1.y; r[6] = (__bf16)x1.z; r[7] = (__bf16)x1.w;
    *(bf16x8*)(xb + (size_t)tid * 8) = r;   // flat idx == tid*8: coalesced
}

// Block (d,g,ks): M = 32 o-rows (CONTIGUOUS in W for fixed g,d), N = 32 b.
// 4 waves: wave w -> (bh = w&1, oh = w>>1) 16x16 output quadrant.
// W staged via global_load_lds (1KB contiguous per instr per o-row);
// XOR chunk-swizzle (row&7)<<4 on source AND lds-read addrs (rule 21).
// mask[o][t] (t = k&63) applied to the A-fragment before bf16 convert.
__global__ __launch_bounds__(256) void gemm_main(const float* __restrict__ W,
                                                 const __bf16* __restrict__ xb,
                                                 const float* __restrict__ mask,
                                                 float* __restrict__ S) {
    __shared__ float ldsW[2][32 * BK];   // 2 x 32 KB
    const int d  = blockIdx.x, g = blockIdx.y, ks = blockIdx.z;
    const int wid  = threadIdx.x >> 6;
    const int lane = threadIdx.x & 63;
    const int bh = wid & 1, oh = wid >> 1;
    const int l15 = lane & 15, g16 = lane >> 4;

    // A-fragment: row r (= o), k-bytes g16*32 + s*128 within step, swizzled
    const int r = oh * 16 + l15;
    const int lds_ro = r * 1024 + ((g16 * 32) ^ ((r & 7) * 16));  // byte offset

    // mask values this lane ever needs: t = (s&1)*32 + g16*8 + j
    const float* mrow = mask + r * T + g16 * 8;
    const float4 me0 = *(const float4*)(mrow);
    const float4 me1 = *(const float4*)(mrow + 4);
    const float4 mo0 = *(const float4*)(mrow + 32);
    const float4 mo1 = *(const float4*)(mrow + 36);

    // XB per-lane base: b-row = bh*16+l15, k-sub g16*8; kt0 = ks*(KCHUNK/32)
    const __bf16* xbl = xb + (size_t)(ks * (KCHUNK / 32)) * 1024
                           + (bh * 16 + l15) * 32 + g16 * 8;

    // staging: wave wid stages rows o = 8*wid..+7 (contiguous 16KB apart)
    const size_t wrow0 = ((size_t)(g * D + d) * O + 8 * wid) * K + (size_t)ks * KCHUNK;

    f32x4 acc = {0.f, 0.f, 0.f, 0.f};

#define STAGE(buf, step)                                                          \
    {                                                                             \
        _Pragma("unroll")                                                         \
        for (int i = 0; i < 8; ++i) {                                             \
            const int row = 8 * wid + i;                                          \
            const char* src = (const char*)(W + wrow0 + (size_t)i * K             \
                                            + (size_t)(step) * BK)                \
                              + ((lane * 16) ^ (i * 16));                         \
            __builtin_amdgcn_global_load_lds(                                     \
                (const __attribute__((address_space(1))) void*)src,               \
                (__attribute__((address_space(3))) void*)((char*)&ldsW[buf][0]    \
                                                          + row * 1024),          \
                16, 0, 0);                                                        \
        }                                                                         \
    }

    STAGE(0, 0);
    __syncthreads();

    int cur = 0;
    for (int step = 0; step < NSTEP; ++step) {
        if (step + 1 < NSTEP) STAGE(cur ^ 1, step + 1);

        const char* lb = (const char*)&ldsW[cur][0];
        const __bf16* xs = xbl + (size_t)(step * 8) * 1024;
        #pragma unroll
        for (int s = 0; s < 8; ++s) {
            const int a0 = lds_ro + s * 128;
            const f32x4 alo = *(const f32x4*)(lb + a0);
            const f32x4 ahi = *(const f32x4*)(lb + (a0 ^ 16));
            const float4 ms0 = (s & 1) ? mo0 : me0;
            const float4 ms1 = (s & 1) ? mo1 : me1;
            bf16x8 af;
            af[0] = (__bf16)(alo[0] * ms0.x); af[1] = (__bf16)(alo[1] * ms0.y);
            af[2] = (__bf16)(alo[2] * ms0.z); af[3] = (__bf16)(alo[3] * ms0.w);
            af[4] = (__bf16)(ahi[0] * ms1.x); af[5] = (__bf16)(ahi[1] * ms1.y);
            af[6] = (__bf16)(ahi[2] * ms1.z); af[7] = (__bf16)(ahi[3] * ms1.w);
            const bf16x8 bfr = *(const bf16x8*)(xs + (size_t)s * 1024);
            acc = __builtin_amdgcn_mfma_f32_16x16x32_bf16(af, bfr, acc, 0, 0, 0);
        }
        __syncthreads();
        cur ^= 1;
    }
#undef STAGE

    // C/D: lane holds D[row=g16*4+i][col=l15]; rows = o (oh half), cols = b (bh half)
    float* Sp = S + (((size_t)(ks * G + g) * D + d) * O + oh * 16) * B + bh * 16;
    #pragma unroll
    for (int i = 0; i < 4; ++i)
        Sp[(g16 * 4 + i) * B + l15] = acc[i];
}

// out[b][d][o] = bias[d][o] + sum_g y[b][g] * sum_ks S[ks][g][d][o][b]
// tid = (d,o,b): S reads fully coalesced; out writes scattered (tiny).
__global__ __launch_bounds__(256) void reduce_out(const float* __restrict__ S,
                                                  const float* __restrict__ y,
                                                  const float* __restrict__ bias,
                                                  float* __restrict__ out) {
    int tid = blockIdx.x * 256 + threadIdx.x;   // 32768 = D*O*B
    int d = tid >> 10, o = (tid >> 5) & 31, b = tid & 31;
    float acc = bias[d * O + o];
    #pragma unroll
    for (int g = 0; g < G; ++g) {
        float s = S[(size_t)g * (D * O * B) + tid]
                + S[(size_t)(G + g) * (D * O * B) + tid];
        acc += y[b * G + g] * s;
    }
    out[b * (D * O) + d * O + o] = acc;
}

extern "C" void kernel_launch(void* const* d_in, const int* in_sizes, int n_in,
                              void* d_out, int out_size, void* d_ws, size_t ws_size,
                              hipStream_t stream) {
    const float* x    = (const float*)d_in[0];
    const float* y    = (const float*)d_in[1];
    const float* w    = (const float*)d_in[2];
    const float* bias = (const float*)d_in[3];
    const float* mask = (const float*)d_in[4];
    float* out = (float*)d_out;

    __bf16* xbp = (__bf16*)d_ws;
    float*  S   = (float*)((char*)d_ws + (size_t)XB_ELEMS * sizeof(__bf16));

    prep_xb<<<64, 256, 0, stream>>>(x, xbp);
    gemm_main<<<dim3(D, G, KSPLIT), 256, 0, stream>>>(w, xbp, mask, S);
    reduce_out<<<128, 256, 0, stream>>>(S, y, bias, out);
}